// Round 9
// baseline (649.849 us; speedup 1.0000x reference)
//
#include <hip/hip_runtime.h>

typedef _Float16 f16;
typedef __attribute__((ext_vector_type(8))) _Float16 half8;
typedef __attribute__((ext_vector_type(2))) _Float16 half2v;
typedef __attribute__((ext_vector_type(4))) float float4v;

#define NNODES 50000
#define NEDGES 800000
#define NREL 8
#define NRSEG (NNODES * NREL)   // 400000 segments (dst, rel)
#define KDIM 1152               // (R+1)*128
#define CAP 16                  // bucket capacity: one 64B cacheline of indices
#define CAPQ (CAP / 4)
#define NTILES (NNODES / 16)    // 3125

// one kernel builds the whole edge structure: count + bucket scatter
__global__ void bucket_fill(const int* __restrict__ src, const int* __restrict__ dst,
                            const int* __restrict__ et, int* __restrict__ cnt,
                            int* __restrict__ esrc) {
    int e = blockIdx.x * blockDim.x + threadIdx.x;
    if (e < NEDGES) {
        int s = dst[e] * NREL + et[e];
        int p = atomicAdd(&cnt[s], 1);
        if (p < CAP) esrc[s * CAP + p] = src[e];
    }
}

// fp32 [N,128] -> fp16 [N,128]
__global__ void cvt_x(const float* __restrict__ x, f16* __restrict__ x16) {
    int t = blockIdx.x * blockDim.x + threadIdx.x;
    if (t >= NNODES * 64) return;
    float2 v = ((const float2*)x)[t];
    half2v o = {(f16)v.x, (f16)v.y};
    ((half2v*)x16)[t] = o;
}

// all 3 layers' weights -> fp16 Bt[h][k]: rows 0..127 L1, 128..255 L2, 256..319 L3
__global__ void prep_w_all(const float* __restrict__ W1, const float* __restrict__ Wr1,
                           const float* __restrict__ W2, const float* __restrict__ Wr2,
                           const float* __restrict__ W3, const float* __restrict__ Wr3,
                           f16* __restrict__ Bt) {
    int idx = blockIdx.x * blockDim.x + threadIdx.x;
    if (idx >= 320 * KDIM) return;
    int hg = idx / KDIM, k = idx - hg * KDIM;
    const float *W, *Wr;
    int h, H;
    if (hg < 128)      { W = W1; Wr = Wr1; h = hg;       H = 128; }
    else if (hg < 256) { W = W2; Wr = Wr2; h = hg - 128; H = 128; }
    else               { W = W3; Wr = Wr3; h = hg - 256; H = 64;  }
    float v = (k < 1024) ? W[(size_t)k * H + h] : Wr[(size_t)(k - 1024) * H + h];
    Bt[idx] = (f16)v;
}

// Fused RGCN layer. 256 threads = 4 INDEPENDENT waves, each owning a 16-node M-tile
// (tile = blockIdx*4 + wave). No LDS, no barriers — wg packaging only exists to get
// past the per-CU workgroup-slot limit that capped 1-wave blocks at ~16 waves/CU.
// Lane (l15, quad) gathers exactly the 32 dims (k = ks*32+quad*8+u) forming its own
// MFMA A-fragments; fp32 accumulate in c[32]; bucket int4 for slot r+1 prefetched
// before slot r's gather. MODE 0: bias+BN+ReLU -> fp16.  MODE 1: bias+sigmoid -> fp32.
template <int H, int MODE>
__global__ __launch_bounds__(256, 4) void fused_layer(
    const f16* __restrict__ act, const f16* __restrict__ Bt,
    const int* __restrict__ cnt, const int* __restrict__ esrc,
    const float* __restrict__ bias, const float* __restrict__ g,
    const float* __restrict__ be, const float* __restrict__ rm,
    const float* __restrict__ rv, f16* __restrict__ hout, float* __restrict__ fout) {
    constexpr int NT = H / 16;  // 8 (H=128) or 4 (H=64)
    const int wave = threadIdx.x >> 6, lane = threadIdx.x & 63;
    const int l15 = lane & 15, quad = lane >> 4;
    const int tile = blockIdx.x * 4 + wave;      // < 3128; >=NTILES waves are dead
    const int m0 = tile * 16;
    int node = m0 + l15;
    node = node < NNODES ? node : NNODES - 1;

    // per-relation counts for this node (two int4, broadcast across quads)
    int4 cq0 = ((const int4*)cnt)[node * 2];
    int4 cq1 = ((const int4*)cnt)[node * 2 + 1];
    int cnts[8] = {cq0.x, cq0.y, cq0.z, cq0.w, cq1.x, cq1.y, cq1.z, cq1.w};

    const int4* bq_base = (const int4*)esrc + (size_t)node * NREL * CAPQ;

    float4v acc[NT];
#pragma unroll
    for (int j = 0; j < NT; ++j) acc[j] = (float4v){0.f, 0.f, 0.f, 0.f};

    int4 qpre = bq_base[0];  // slot 0, first 4 indices

#pragma unroll
    for (int r = 0; r < 8; ++r) {
        int truelen = cnts[r];
        int len = truelen < CAP ? truelen : CAP;
        float inv = truelen > 1 ? 1.f / (float)truelen : 1.f;
        const int4* bq = bq_base + r * CAPQ;
        int4 q0 = qpre;
        if (r < 7) qpre = bq_base[(r + 1) * CAPQ];  // prefetch next slot's bucket head
        float c[32];
#pragma unroll
        for (int t = 0; t < 32; ++t) c[t] = 0.f;
        for (int j4 = 0; j4 < (len + 3) >> 2; ++j4) {
            int4 q = (j4 == 0) ? q0 : bq[j4];
            int ids[4] = {q.x, q.y, q.z, q.w};
            int base = j4 * 4;
#pragma unroll
            for (int t = 0; t < 4; ++t) {
                if (base + t < len) {
                    // 4 half8 loads at 64B stride; quads 0..3 tile each 64B chunk
                    const half8* rp = (const half8*)(act + (size_t)ids[t] * 128 + quad * 8);
                    half8 v0 = rp[0], v1 = rp[4], v2 = rp[8], v3 = rp[12];
#pragma unroll
                    for (int u = 0; u < 8; ++u) {
                        c[u] += (float)v0[u];
                        c[8 + u] += (float)v1[u];
                        c[16 + u] += (float)v2[u];
                        c[24 + u] += (float)v3[u];
                    }
                }
            }
        }
        half8 af[4];
#pragma unroll
        for (int ks = 0; ks < 4; ++ks)
#pragma unroll
            for (int u = 0; u < 8; ++u) af[ks][u] = (f16)(c[ks * 8 + u] * inv);
#pragma unroll
        for (int ks = 0; ks < 4; ++ks) {
#pragma unroll
            for (int nt = 0; nt < NT; ++nt) {
                half8 bf = *(const half8*)(Bt + (size_t)(nt * 16 + l15) * KDIM +
                                           r * 128 + ks * 32 + quad * 8);
                acc[nt] = __builtin_amdgcn_mfma_f32_16x16x32_f16(af[ks], bf, acc[nt], 0, 0, 0);
            }
        }
    }

    // root slot: A fragments direct from act (lane's own node row)
#pragma unroll
    for (int ks = 0; ks < 4; ++ks) {
        half8 af = *(const half8*)(act + (size_t)node * 128 + ks * 32 + quad * 8);
#pragma unroll
        for (int nt = 0; nt < NT; ++nt) {
            half8 bf = *(const half8*)(Bt + (size_t)(nt * 16 + l15) * KDIM +
                                       1024 + ks * 32 + quad * 8);
            acc[nt] = __builtin_amdgcn_mfma_f32_16x16x32_f16(af, bf, acc[nt], 0, 0, 0);
        }
    }

    // epilogue: D[m = quad*4+rg][n = l15] per n-tile
#pragma unroll
    for (int nt = 0; nt < NT; ++nt) {
        int col = nt * 16 + l15;
        float alpha, beta;
        if (MODE == 0) {
            float sc = g[col] * rsqrtf(rv[col] + 1e-5f);
            alpha = sc;
            beta = (bias[col] - rm[col]) * sc + be[col];
        } else {
            alpha = 1.f;
            beta = bias[col];
        }
#pragma unroll
        for (int rg = 0; rg < 4; ++rg) {
            int row = m0 + quad * 4 + rg;
            if (row < NNODES) {
                float v = fmaf(acc[nt][rg], alpha, beta);
                if (MODE == 0) {
                    hout[(size_t)row * H + col] = (f16)fmaxf(v, 0.f);
                } else {
                    fout[(size_t)row * H + col] = 1.f / (1.f + __expf(-v));
                }
            }
        }
    }
}

extern "C" void kernel_launch(void* const* d_in, const int* in_sizes, int n_in,
                              void* d_out, int out_size, void* d_ws, size_t ws_size,
                              hipStream_t stream) {
    (void)in_sizes; (void)n_in; (void)out_size; (void)ws_size;
    const float* x   = (const float*)d_in[0];
    const int* ei    = (const int*)d_in[1];
    const int* et    = (const int*)d_in[2];
    const float* W1  = (const float*)d_in[3];
    const float* Wr1 = (const float*)d_in[4];
    const float* b1  = (const float*)d_in[5];
    const float* g1  = (const float*)d_in[6];
    const float* be1 = (const float*)d_in[7];
    const float* rm1 = (const float*)d_in[8];
    const float* rv1 = (const float*)d_in[9];
    const float* W2  = (const float*)d_in[10];
    const float* Wr2 = (const float*)d_in[11];
    const float* b2  = (const float*)d_in[12];
    const float* g2  = (const float*)d_in[13];
    const float* be2 = (const float*)d_in[14];
    const float* rm2 = (const float*)d_in[15];
    const float* rv2 = (const float*)d_in[16];
    const float* W3  = (const float*)d_in[17];
    const float* Wr3 = (const float*)d_in[18];
    const float* b3  = (const float*)d_in[19];
    const int* src = ei;
    const int* dst = ei + NEDGES;
    float* out = (float*)d_out;

    char* ws = (char*)d_ws;
    size_t off = 0;
    auto alloc = [&](size_t bytes) -> void* {
        off = (off + 255) & ~(size_t)255;
        void* p = ws + off;
        off += bytes;
        return p;
    };
    int* cnt  = (int*)alloc((size_t)NRSEG * 4);             // 1.6 MB
    int* esrc = (int*)alloc((size_t)NRSEG * CAP * 4);       // 25.6 MB
    f16* x16  = (f16*)alloc((size_t)NNODES * 128 * 2);      // 12.8 MB
    f16* ha   = (f16*)alloc((size_t)NNODES * 128 * 2);
    f16* hb   = (f16*)alloc((size_t)NNODES * 128 * 2);
    f16* Bt   = (f16*)alloc((size_t)320 * KDIM * 2);        // 0.74 MB (L1|L2|L3)

    hipMemsetAsync(cnt, 0, (size_t)NRSEG * 4, stream);
    bucket_fill<<<(NEDGES + 255) / 256, 256, 0, stream>>>(src, dst, et, cnt, esrc);

    const int EL_BLOCKS = (NNODES * 64 + 255) / 256;
    const int GB = (NTILES + 3) / 4;  // 782 blocks x 4 independent waves
    cvt_x<<<EL_BLOCKS, 256, 0, stream>>>(x, x16);
    prep_w_all<<<(320 * KDIM + 255) / 256, 256, 0, stream>>>(W1, Wr1, W2, Wr2, W3, Wr3, Bt);

    fused_layer<128, 0><<<GB, 256, 0, stream>>>(x16, Bt, cnt, esrc,
                                                b1, g1, be1, rm1, rv1, ha, nullptr);
    fused_layer<128, 0><<<GB, 256, 0, stream>>>(ha, Bt + (size_t)128 * KDIM, cnt, esrc,
                                                b2, g2, be2, rm2, rv2, hb, nullptr);
    fused_layer<64, 1><<<GB, 256, 0, stream>>>(hb, Bt + (size_t)256 * KDIM, cnt, esrc,
                                               b3, nullptr, nullptr, nullptr, nullptr,
                                               nullptr, out);
}

// Round 10
// 551.789 us; speedup vs baseline: 1.1777x; 1.1777x over previous
//
#include <hip/hip_runtime.h>

typedef _Float16 f16;
typedef __attribute__((ext_vector_type(8))) _Float16 half8;
typedef __attribute__((ext_vector_type(2))) _Float16 half2v;
typedef __attribute__((ext_vector_type(4))) float float4v;

#define NNODES 50000
#define NEDGES 800000
#define NREL 8
#define NRSEG (NNODES * NREL)   // 400000 segments (dst, rel)
#define KDIM 1152               // (R+1)*128
#define CAP 16                  // bucket capacity: one 64B cacheline of indices
#define CAPQ (CAP / 4)
#define NTILES (NNODES / 16)    // 3125 exactly -> no bounds checks anywhere

// one kernel builds the whole edge structure: count + bucket scatter
__global__ void bucket_fill(const int* __restrict__ src, const int* __restrict__ dst,
                            const int* __restrict__ et, int* __restrict__ cnt,
                            int* __restrict__ esrc) {
    int e = blockIdx.x * blockDim.x + threadIdx.x;
    if (e < NEDGES) {
        int s = dst[e] * NREL + et[e];
        int p = atomicAdd(&cnt[s], 1);
        if (p < CAP) esrc[s * CAP + p] = src[e];
    }
}

// fp32 [N,128] -> fp16 [N,128]
__global__ void cvt_x(const float* __restrict__ x, f16* __restrict__ x16) {
    int t = blockIdx.x * blockDim.x + threadIdx.x;
    if (t >= NNODES * 64) return;
    float2 v = ((const float2*)x)[t];
    half2v o = {(f16)v.x, (f16)v.y};
    ((half2v*)x16)[t] = o;
}

// all 3 layers' weights -> fp16 Bt[h][k]: rows 0..127 L1, 128..255 L2, 256..319 L3
__global__ void prep_w_all(const float* __restrict__ W1, const float* __restrict__ Wr1,
                           const float* __restrict__ W2, const float* __restrict__ Wr2,
                           const float* __restrict__ W3, const float* __restrict__ Wr3,
                           f16* __restrict__ Bt) {
    int idx = blockIdx.x * blockDim.x + threadIdx.x;
    if (idx >= 320 * KDIM) return;
    int hg = idx / KDIM, k = idx - hg * KDIM;
    const float *W, *Wr;
    int h, H;
    if (hg < 128)      { W = W1; Wr = Wr1; h = hg;       H = 128; }
    else if (hg < 256) { W = W2; Wr = Wr2; h = hg - 128; H = 128; }
    else               { W = W3; Wr = Wr3; h = hg - 256; H = 64;  }
    float v = (k < 1024) ? W[(size_t)k * H + h] : Wr[(size_t)(k - 1024) * H + h];
    Bt[idx] = (f16)v;
}

// Fused RGCN layer with 4-way K-SPLIT: one 256-thread block per 16-node tile
// (grid 3125 -> 12500 waves, oversubscribing the 8192-wave chip). Wave w handles
// relations {2w, 2w+1}; wave 3 also the root slot (no gather). Lane (l15, quad)
// gathers the 32 dims forming its own MFMA A-fragments (fp32 c[32], fp16 convert,
// MFMA vs L1-resident Bt). Partial accs combined in padded LDS fp32 tile over 4
// barrier rounds; cooperative epilogue. MODE 0: bias+BN+ReLU -> fp16. MODE 1: sigmoid -> fp32.
template <int H, int MODE>
__global__ __launch_bounds__(256, 4) void fused_layer(
    const f16* __restrict__ act, const f16* __restrict__ Bt,
    const int* __restrict__ cnt, const int* __restrict__ esrc,
    const float* __restrict__ bias, const float* __restrict__ g,
    const float* __restrict__ be, const float* __restrict__ rm,
    const float* __restrict__ rv, f16* __restrict__ hout, float* __restrict__ fout) {
    constexpr int NT = H / 16;  // 8 (H=128) or 4 (H=64)
    __shared__ float Facc[16][H + 4];  // +4 pad: spreads quads across banks in reduce
    const int tid = threadIdx.x;
    const int wave = tid >> 6, lane = tid & 63;
    const int l15 = lane & 15, quad = lane >> 4;
    const int m0 = blockIdx.x * 16;
    const int node = m0 + l15;  // < 50000 always (3125*16 exact)

    // this wave's two relation counts (8B load)
    int2 c2 = ((const int2*)cnt)[node * 4 + wave];
    int cw[2] = {c2.x, c2.y};
    const int4* bq_base = (const int4*)esrc + (size_t)node * NREL * CAPQ;

    float4v acc[NT];
#pragma unroll
    for (int j = 0; j < NT; ++j) acc[j] = (float4v){0.f, 0.f, 0.f, 0.f};

    // prefetch both slots' bucket heads up front (independent loads)
    int4 q0a = bq_base[(wave * 2) * CAPQ];
    int4 q0b = bq_base[(wave * 2 + 1) * CAPQ];

#pragma unroll
    for (int rr = 0; rr < 2; ++rr) {
        int r = wave * 2 + rr;
        int truelen = cw[rr];
        int len = truelen < CAP ? truelen : CAP;
        float inv = truelen > 1 ? 1.f / (float)truelen : 1.f;
        const int4* bq = bq_base + r * CAPQ;
        float c[32];
#pragma unroll
        for (int t = 0; t < 32; ++t) c[t] = 0.f;
        for (int j4 = 0; j4 < (len + 3) >> 2; ++j4) {
            int4 q = (j4 == 0) ? (rr == 0 ? q0a : q0b) : bq[j4];
            int ids[4] = {q.x, q.y, q.z, q.w};
            int base = j4 * 4;
#pragma unroll
            for (int t = 0; t < 4; ++t) {
                if (base + t < len) {
                    // 4 half8 loads at 64B stride; quads 0..3 tile each 64B chunk
                    const half8* rp = (const half8*)(act + (size_t)ids[t] * 128 + quad * 8);
                    half8 v0 = rp[0], v1 = rp[4], v2 = rp[8], v3 = rp[12];
#pragma unroll
                    for (int u = 0; u < 8; ++u) {
                        c[u] += (float)v0[u];
                        c[8 + u] += (float)v1[u];
                        c[16 + u] += (float)v2[u];
                        c[24 + u] += (float)v3[u];
                    }
                }
            }
        }
        half8 af[4];
#pragma unroll
        for (int ks = 0; ks < 4; ++ks)
#pragma unroll
            for (int u = 0; u < 8; ++u) af[ks][u] = (f16)(c[ks * 8 + u] * inv);
#pragma unroll
        for (int ks = 0; ks < 4; ++ks) {
#pragma unroll
            for (int nt = 0; nt < NT; ++nt) {
                half8 bf = *(const half8*)(Bt + (size_t)(nt * 16 + l15) * KDIM +
                                           r * 128 + ks * 32 + quad * 8);
                acc[nt] = __builtin_amdgcn_mfma_f32_16x16x32_f16(af[ks], bf, acc[nt], 0, 0, 0);
            }
        }
    }

    // root slot on wave 3 (direct act read, no gather)
    if (wave == 3) {
#pragma unroll
        for (int ks = 0; ks < 4; ++ks) {
            half8 af = *(const half8*)(act + (size_t)node * 128 + ks * 32 + quad * 8);
#pragma unroll
            for (int nt = 0; nt < NT; ++nt) {
                half8 bf = *(const half8*)(Bt + (size_t)(nt * 16 + l15) * KDIM +
                                           1024 + ks * 32 + quad * 8);
                acc[nt] = __builtin_amdgcn_mfma_f32_16x16x32_f16(af, bf, acc[nt], 0, 0, 0);
            }
        }
    }

    // combine the 4 partial accumulators in LDS (barrier-gated rounds)
#pragma unroll
    for (int w = 0; w < 4; ++w) {
        __syncthreads();
        if (wave == w) {
#pragma unroll
            for (int nt = 0; nt < NT; ++nt)
#pragma unroll
                for (int rg = 0; rg < 4; ++rg) {
                    float* p = &Facc[quad * 4 + rg][nt * 16 + l15];
                    if (w == 0) *p = acc[nt][rg];
                    else *p += acc[nt][rg];
                }
        }
    }
    __syncthreads();

    // cooperative epilogue: thread -> (row = tid>>4, E cols at (tid&15)*E)
    constexpr int E = 16 * H / 256;  // 8 (H=128) or 4 (H=64)
    {
        int row = tid >> 4, col0 = (tid & 15) * E;
        int grow = m0 + row;
        if (MODE == 0) {
            half8 o;
#pragma unroll
            for (int j = 0; j < E; ++j) {
                int col = col0 + j;
                float sc = g[col] * rsqrtf(rv[col] + 1e-5f);
                float beta = (bias[col] - rm[col]) * sc + be[col];
                float v = fmaf(Facc[row][col], sc, beta);
                o[j] = (f16)fmaxf(v, 0.f);
            }
            *(half8*)(hout + (size_t)grow * H + col0) = o;
        } else {
            float4v o;
#pragma unroll
            for (int j = 0; j < E; ++j) {
                int col = col0 + j;
                float v = Facc[row][col] + bias[col];
                o[j] = 1.f / (1.f + __expf(-v));
            }
            *(float4v*)(fout + (size_t)grow * H + col0) = o;
        }
    }
}

extern "C" void kernel_launch(void* const* d_in, const int* in_sizes, int n_in,
                              void* d_out, int out_size, void* d_ws, size_t ws_size,
                              hipStream_t stream) {
    (void)in_sizes; (void)n_in; (void)out_size; (void)ws_size;
    const float* x   = (const float*)d_in[0];
    const int* ei    = (const int*)d_in[1];
    const int* et    = (const int*)d_in[2];
    const float* W1  = (const float*)d_in[3];
    const float* Wr1 = (const float*)d_in[4];
    const float* b1  = (const float*)d_in[5];
    const float* g1  = (const float*)d_in[6];
    const float* be1 = (const float*)d_in[7];
    const float* rm1 = (const float*)d_in[8];
    const float* rv1 = (const float*)d_in[9];
    const float* W2  = (const float*)d_in[10];
    const float* Wr2 = (const float*)d_in[11];
    const float* b2  = (const float*)d_in[12];
    const float* g2  = (const float*)d_in[13];
    const float* be2 = (const float*)d_in[14];
    const float* rm2 = (const float*)d_in[15];
    const float* rv2 = (const float*)d_in[16];
    const float* W3  = (const float*)d_in[17];
    const float* Wr3 = (const float*)d_in[18];
    const float* b3  = (const float*)d_in[19];
    const int* src = ei;
    const int* dst = ei + NEDGES;
    float* out = (float*)d_out;

    char* ws = (char*)d_ws;
    size_t off = 0;
    auto alloc = [&](size_t bytes) -> void* {
        off = (off + 255) & ~(size_t)255;
        void* p = ws + off;
        off += bytes;
        return p;
    };
    int* cnt  = (int*)alloc((size_t)NRSEG * 4);             // 1.6 MB
    int* esrc = (int*)alloc((size_t)NRSEG * CAP * 4);       // 25.6 MB
    f16* x16  = (f16*)alloc((size_t)NNODES * 128 * 2);      // 12.8 MB
    f16* ha   = (f16*)alloc((size_t)NNODES * 128 * 2);
    f16* hb   = (f16*)alloc((size_t)NNODES * 128 * 2);
    f16* Bt   = (f16*)alloc((size_t)320 * KDIM * 2);        // 0.74 MB (L1|L2|L3)

    hipMemsetAsync(cnt, 0, (size_t)NRSEG * 4, stream);
    bucket_fill<<<(NEDGES + 255) / 256, 256, 0, stream>>>(src, dst, et, cnt, esrc);

    const int EL_BLOCKS = (NNODES * 64 + 255) / 256;
    cvt_x<<<EL_BLOCKS, 256, 0, stream>>>(x, x16);
    prep_w_all<<<(320 * KDIM + 255) / 256, 256, 0, stream>>>(W1, Wr1, W2, Wr2, W3, Wr3, Bt);

    fused_layer<128, 0><<<NTILES, 256, 0, stream>>>(x16, Bt, cnt, esrc,
                                                    b1, g1, be1, rm1, rv1, ha, nullptr);
    fused_layer<128, 0><<<NTILES, 256, 0, stream>>>(ha, Bt + (size_t)128 * KDIM, cnt, esrc,
                                                    b2, g2, be2, rm2, rv2, hb, nullptr);
    fused_layer<64, 1><<<NTILES, 256, 0, stream>>>(hb, Bt + (size_t)256 * KDIM, cnt, esrc,
                                                   b3, nullptr, nullptr, nullptr, nullptr,
                                                   nullptr, out);
}

// Round 11
// 477.940 us; speedup vs baseline: 1.3597x; 1.1545x over previous
//
#include <hip/hip_runtime.h>

typedef _Float16 f16;
typedef __attribute__((ext_vector_type(8))) _Float16 half8;
typedef __attribute__((ext_vector_type(2))) _Float16 half2v;
typedef __attribute__((ext_vector_type(4))) float float4v;

#define NNODES 50000
#define NEDGES 800000
#define NREL 8
#define NRSEG (NNODES * NREL)   // 400000 segments (dst, rel)
#define KDIM 1152               // (R+1)*128
#define CAP 16                  // bucket capacity: one 64B cacheline of indices
#define CAPQ (CAP / 4)
#define NT64 ((NNODES + 63) / 64)  // 782 tiles of 64 nodes

// one kernel builds the whole edge structure: count + bucket scatter
__global__ void bucket_fill(const int* __restrict__ src, const int* __restrict__ dst,
                            const int* __restrict__ et, int* __restrict__ cnt,
                            int* __restrict__ esrc) {
    int e = blockIdx.x * blockDim.x + threadIdx.x;
    if (e < NEDGES) {
        int s = dst[e] * NREL + et[e];
        int p = atomicAdd(&cnt[s], 1);
        if (p < CAP) esrc[s * CAP + p] = src[e];
    }
}

// fp32 [N,128] -> fp16 [N,128]
__global__ void cvt_x(const float* __restrict__ x, f16* __restrict__ x16) {
    int t = blockIdx.x * blockDim.x + threadIdx.x;
    if (t >= NNODES * 64) return;
    float2 v = ((const float2*)x)[t];
    half2v o = {(f16)v.x, (f16)v.y};
    ((half2v*)x16)[t] = o;
}

// all 3 layers' weights -> fp16 Bt[h][k]: rows 0..127 L1, 128..255 L2, 256..319 L3
__global__ void prep_w_all(const float* __restrict__ W1, const float* __restrict__ Wr1,
                           const float* __restrict__ W2, const float* __restrict__ Wr2,
                           const float* __restrict__ W3, const float* __restrict__ Wr3,
                           f16* __restrict__ Bt) {
    int idx = blockIdx.x * blockDim.x + threadIdx.x;
    if (idx >= 320 * KDIM) return;
    int hg = idx / KDIM, k = idx - hg * KDIM;
    const float *W, *Wr;
    int h, H;
    if (hg < 128)      { W = W1; Wr = Wr1; h = hg;       H = 128; }
    else if (hg < 256) { W = W2; Wr = Wr2; h = hg - 128; H = 128; }
    else               { W = W3; Wr = Wr3; h = hg - 256; H = 64;  }
    float v = (k < 1024) ? W[(size_t)k * H + h] : Wr[(size_t)(k - 1024) * H + h];
    Bt[idx] = (f16)v;
}

// Fused RGCN layer, N-SPLIT + LDS WEIGHT STAGING.
// Block = (64-node tile, n-half of HALF=H/2 cols): 4 waves, wave w owns nodes
// [tile*64+16w, +16). Per slot r (8 rels + root): cooperative stage of the 16 KB
// weight slice into XOR-swizzled LDS (shared by 4 waves — kills the per-wave Bt
// re-read that congested L2), gather into c[32] regs (round-8 layout: lane (l15,quad)
// owns the 32 dims of its own MFMA A-frags), 2 barriers, MFMA from LDS.
// MODE 0: bias+BN+ReLU -> fp16.  MODE 1: bias+sigmoid -> fp32.
template <int H, int MODE>
__global__ __launch_bounds__(256, 4) void fused_layer(
    const f16* __restrict__ act, const f16* __restrict__ Bt,
    const int* __restrict__ cnt, const int* __restrict__ esrc,
    const float* __restrict__ bias, const float* __restrict__ g,
    const float* __restrict__ be, const float* __restrict__ rm,
    const float* __restrict__ rv, f16* __restrict__ hout, float* __restrict__ fout) {
    constexpr int HALF = H / 2;          // cols per block (64 or 32)
    constexpr int NT = HALF / 16;        // n-tiles per wave (4 or 2)
    constexpr int NG = HALF * 16 / 256;  // staging granules per thread (4 or 2)
    __shared__ f16 Ws[HALF][128];        // 16 KB (8 KB for H=64), XOR-swizzled granules
    const int tid = threadIdx.x;
    const int wave = tid >> 6, lane = tid & 63;
    const int l15 = lane & 15, quad = lane >> 4;
    const int m0 = blockIdx.x * 64 + wave * 16;  // this wave's 16 nodes
    const int nh = blockIdx.y;
    int node = m0 + l15;
    node = node < NNODES ? node : NNODES - 1;

    // per-relation counts for this node (two int4, broadcast across quads)
    int4 cq0 = ((const int4*)cnt)[node * 2];
    int4 cq1 = ((const int4*)cnt)[node * 2 + 1];
    int cnts[8] = {cq0.x, cq0.y, cq0.z, cq0.w, cq1.x, cq1.y, cq1.z, cq1.w};
    const int4* bq_base = (const int4*)esrc + (size_t)node * NREL * CAPQ;

    float4v acc[NT];
#pragma unroll
    for (int j = 0; j < NT; ++j) acc[j] = (float4v){0.f, 0.f, 0.f, 0.f};

    int4 qpre = bq_base[0];  // slot 0 bucket head
    half8 af_root[4];

#pragma unroll
    for (int r = 0; r < 9; ++r) {
        __syncthreads();  // all waves done reading Ws of slot r-1
        // ---- cooperative stage of weight slice r into swizzled LDS ----
#pragma unroll
        for (int i = 0; i < NG; ++i) {
            int G = i * 256 + tid;       // granule id: row = G>>4, g = G&15
            int row = G >> 4, gg = G & 15;
            half8 v = *(const half8*)(Bt + (size_t)(nh * HALF + row) * KDIM +
                                      r * 128 + gg * 8);
            *(half8*)&Ws[row][((gg ^ (row & 7))) * 8] = v;
        }
        // ---- gather phase (overlaps staging latency) ----
        float c[32];
        if (r < 8) {
            int truelen = cnts[r];
            int len = truelen < CAP ? truelen : CAP;
            float inv = truelen > 1 ? 1.f / (float)truelen : 1.f;
            const int4* bq = bq_base + r * CAPQ;
            int4 q0 = qpre;
            if (r < 7) qpre = bq_base[(r + 1) * CAPQ];  // prefetch next slot's head
#pragma unroll
            for (int t = 0; t < 32; ++t) c[t] = 0.f;
            for (int j4 = 0; j4 < (len + 3) >> 2; ++j4) {
                int4 q = (j4 == 0) ? q0 : bq[j4];
                int ids[4] = {q.x, q.y, q.z, q.w};
                int base = j4 * 4;
#pragma unroll
                for (int t = 0; t < 4; ++t) {
                    if (base + t < len) {
                        // 4 half8 loads at 64B stride; quads 0..3 tile each 64B chunk
                        const half8* rp = (const half8*)(act + (size_t)ids[t] * 128 + quad * 8);
                        half8 v0 = rp[0], v1 = rp[4], v2 = rp[8], v3 = rp[12];
#pragma unroll
                        for (int u = 0; u < 8; ++u) {
                            c[u] += (float)v0[u];
                            c[8 + u] += (float)v1[u];
                            c[16 + u] += (float)v2[u];
                            c[24 + u] += (float)v3[u];
                        }
                    }
                }
            }
#pragma unroll
            for (int t = 0; t < 32; ++t) c[t] *= inv;
        } else {
            // root slot: prefetch own act row (A-frag layout matches directly)
#pragma unroll
            for (int ks = 0; ks < 4; ++ks)
                af_root[ks] = *(const half8*)(act + (size_t)node * 128 + ks * 32 + quad * 8);
        }
        __syncthreads();  // Ws visible
        // ---- MFMA from LDS ----
#pragma unroll
        for (int ks = 0; ks < 4; ++ks) {
            half8 af;
            if (r < 8) {
#pragma unroll
                for (int u = 0; u < 8; ++u) af[u] = (f16)c[ks * 8 + u];
            } else {
                af = af_root[ks];
            }
#pragma unroll
            for (int nt = 0; nt < NT; ++nt) {
                int row = nt * 16 + l15;
                half8 bf = *(const half8*)&Ws[row][(((ks * 4 + quad) ^ (row & 7))) * 8];
                acc[nt] = __builtin_amdgcn_mfma_f32_16x16x32_f16(af, bf, acc[nt], 0, 0, 0);
            }
        }
    }

    // ---- epilogue: D[m = quad*4+rg][n = l15] per n-tile ----
#pragma unroll
    for (int nt = 0; nt < NT; ++nt) {
        int col = nh * HALF + nt * 16 + l15;
        float alpha, beta;
        if (MODE == 0) {
            float sc = g[col] * rsqrtf(rv[col] + 1e-5f);
            alpha = sc;
            beta = (bias[col] - rm[col]) * sc + be[col];
        } else {
            alpha = 1.f;
            beta = bias[col];
        }
#pragma unroll
        for (int rg = 0; rg < 4; ++rg) {
            int row = m0 + quad * 4 + rg;
            if (row < NNODES) {
                float v = fmaf(acc[nt][rg], alpha, beta);
                if (MODE == 0) {
                    hout[(size_t)row * H + col] = (f16)fmaxf(v, 0.f);
                } else {
                    fout[(size_t)row * H + col] = 1.f / (1.f + __expf(-v));
                }
            }
        }
    }
}

extern "C" void kernel_launch(void* const* d_in, const int* in_sizes, int n_in,
                              void* d_out, int out_size, void* d_ws, size_t ws_size,
                              hipStream_t stream) {
    (void)in_sizes; (void)n_in; (void)out_size; (void)ws_size;
    const float* x   = (const float*)d_in[0];
    const int* ei    = (const int*)d_in[1];
    const int* et    = (const int*)d_in[2];
    const float* W1  = (const float*)d_in[3];
    const float* Wr1 = (const float*)d_in[4];
    const float* b1  = (const float*)d_in[5];
    const float* g1  = (const float*)d_in[6];
    const float* be1 = (const float*)d_in[7];
    const float* rm1 = (const float*)d_in[8];
    const float* rv1 = (const float*)d_in[9];
    const float* W2  = (const float*)d_in[10];
    const float* Wr2 = (const float*)d_in[11];
    const float* b2  = (const float*)d_in[12];
    const float* g2  = (const float*)d_in[13];
    const float* be2 = (const float*)d_in[14];
    const float* rm2 = (const float*)d_in[15];
    const float* rv2 = (const float*)d_in[16];
    const float* W3  = (const float*)d_in[17];
    const float* Wr3 = (const float*)d_in[18];
    const float* b3  = (const float*)d_in[19];
    const int* src = ei;
    const int* dst = ei + NEDGES;
    float* out = (float*)d_out;

    char* ws = (char*)d_ws;
    size_t off = 0;
    auto alloc = [&](size_t bytes) -> void* {
        off = (off + 255) & ~(size_t)255;
        void* p = ws + off;
        off += bytes;
        return p;
    };
    int* cnt  = (int*)alloc((size_t)NRSEG * 4);             // 1.6 MB
    int* esrc = (int*)alloc((size_t)NRSEG * CAP * 4);       // 25.6 MB
    f16* x16  = (f16*)alloc((size_t)NNODES * 128 * 2);      // 12.8 MB
    f16* ha   = (f16*)alloc((size_t)NNODES * 128 * 2);
    f16* hb   = (f16*)alloc((size_t)NNODES * 128 * 2);
    f16* Bt   = (f16*)alloc((size_t)320 * KDIM * 2);        // 0.74 MB (L1|L2|L3)

    hipMemsetAsync(cnt, 0, (size_t)NRSEG * 4, stream);
    bucket_fill<<<(NEDGES + 255) / 256, 256, 0, stream>>>(src, dst, et, cnt, esrc);

    const int EL_BLOCKS = (NNODES * 64 + 255) / 256;
    cvt_x<<<EL_BLOCKS, 256, 0, stream>>>(x, x16);
    prep_w_all<<<(320 * KDIM + 255) / 256, 256, 0, stream>>>(W1, Wr1, W2, Wr2, W3, Wr3, Bt);

    fused_layer<128, 0><<<dim3(NT64, 2), 256, 0, stream>>>(x16, Bt, cnt, esrc,
                                                           b1, g1, be1, rm1, rv1, ha, nullptr);
    fused_layer<128, 0><<<dim3(NT64, 2), 256, 0, stream>>>(ha, Bt + (size_t)128 * KDIM, cnt, esrc,
                                                           b2, g2, be2, rm2, rv2, hb, nullptr);
    fused_layer<64, 1><<<dim3(NT64, 2), 256, 0, stream>>>(hb, Bt + (size_t)256 * KDIM, cnt, esrc,
                                                          b3, nullptr, nullptr, nullptr, nullptr,
                                                          nullptr, out);
}

// Round 12
// 476.742 us; speedup vs baseline: 1.3631x; 1.0025x over previous
//
#include <hip/hip_runtime.h>

typedef _Float16 f16;
typedef __attribute__((ext_vector_type(8))) _Float16 half8;
typedef __attribute__((ext_vector_type(2))) _Float16 half2v;
typedef __attribute__((ext_vector_type(4))) float float4v;

#define NNODES 50000
#define NEDGES 800000
#define NREL 8
#define NRSEG (NNODES * NREL)   // 400000 segments (dst, rel)
#define KDIM 1152               // (R+1)*128
#define CAP 16                  // bucket capacity: one 64B cacheline of indices
#define CAPQ (CAP / 4)
#define NT64 ((NNODES + 63) / 64)  // 782 tiles of 64 nodes

// one kernel builds the whole edge structure: count + bucket scatter
__global__ void bucket_fill(const int* __restrict__ src, const int* __restrict__ dst,
                            const int* __restrict__ et, int* __restrict__ cnt,
                            int* __restrict__ esrc) {
    int e = blockIdx.x * blockDim.x + threadIdx.x;
    if (e < NEDGES) {
        int s = dst[e] * NREL + et[e];
        int p = atomicAdd(&cnt[s], 1);
        if (p < CAP) esrc[s * CAP + p] = src[e];
    }
}

// merged setup: threads [0, N*64) convert x -> fp16; the rest build fp16 Bt
// Bt rows 0..127 = L1 (W1|Wr1), 128..255 = L2, 256..319 = L3.
__global__ void setup_misc(const float* __restrict__ x, f16* __restrict__ x16,
                           const float* __restrict__ W1, const float* __restrict__ Wr1,
                           const float* __restrict__ W2, const float* __restrict__ Wr2,
                           const float* __restrict__ W3, const float* __restrict__ Wr3,
                           f16* __restrict__ Bt) {
    int t = blockIdx.x * blockDim.x + threadIdx.x;
    if (t < NNODES * 64) {
        float2 v = ((const float2*)x)[t];
        half2v o = {(f16)v.x, (f16)v.y};
        ((half2v*)x16)[t] = o;
        return;
    }
    int idx = t - NNODES * 64;
    if (idx >= 320 * KDIM) return;
    int hg = idx / KDIM, k = idx - hg * KDIM;
    const float *W, *Wr;
    int h, H;
    if (hg < 128)      { W = W1; Wr = Wr1; h = hg;       H = 128; }
    else if (hg < 256) { W = W2; Wr = Wr2; h = hg - 128; H = 128; }
    else               { W = W3; Wr = Wr3; h = hg - 256; H = 64;  }
    float v = (k < 1024) ? W[(size_t)k * H + h] : Wr[(size_t)(k - 1024) * H + h];
    Bt[idx] = (f16)v;
}

// Fused RGCN layer: ONE 512-thread block per 64-node tile, full H (single gather).
// Per slot r (8 rels + root): stage full weight slice (H x 128, XOR-swizzled) into Ws;
// gather phase uses all 512 threads as (seg = tid>>3, 16-dim part = tid&7) -> each
// edge row is a 256B burst over 8 adjacent lanes, read ONCE per layer; fp32 c[16],
// fp16 means into swizzled Ms (shared by both n-halves). MFMA: wave w -> m-tile (w&3),
// n-half (w>>2); af from Ms, bf from Ws. Root slot: af direct from act.
// MODE 0: bias+BN+ReLU -> fp16.  MODE 1: bias+sigmoid -> fp32.
template <int H, int MODE>
__global__ __launch_bounds__(512, 6) void fused_layer(
    const f16* __restrict__ act, const f16* __restrict__ Bt,
    const int* __restrict__ cnt, const int* __restrict__ esrc,
    const float* __restrict__ bias, const float* __restrict__ g,
    const float* __restrict__ be, const float* __restrict__ rm,
    const float* __restrict__ rv, f16* __restrict__ hout, float* __restrict__ fout) {
    constexpr int NT = H / 32;          // n-tiles per wave (4 or 2)
    constexpr int NG = H * 16 / 512;    // weight granules per thread (4 or 2)
    __shared__ f16 Ms[64][128];         // 16 KB mean tile, XOR-swizzled granules
    __shared__ f16 Ws[H][128];          // 32 KB (16 KB for H=64), XOR-swizzled
    const int tid = threadIdx.x;
    const int wave = tid >> 6, lane = tid & 63;
    const int l15 = lane & 15, quad = lane >> 4;
    const int m0 = blockIdx.x * 64;
    const int seg = tid >> 3, p8 = tid & 7;      // gather task
    const int mt = wave & 3, nh = wave >> 2;     // MFMA ownership
    int node = m0 + seg;
    node = node < NNODES ? node : NNODES - 1;

    // per-relation counts for this thread's segment-node (8 threads broadcast-share)
    int4 cq0 = ((const int4*)cnt)[node * 2];
    int4 cq1 = ((const int4*)cnt)[node * 2 + 1];
    int cnts[8] = {cq0.x, cq0.y, cq0.z, cq0.w, cq1.x, cq1.y, cq1.z, cq1.w};
    const int4* bq_base = (const int4*)esrc + (size_t)node * NREL * CAPQ;

    float4v acc[NT];
#pragma unroll
    for (int j = 0; j < NT; ++j) acc[j] = (float4v){0.f, 0.f, 0.f, 0.f};

    int4 qpre = bq_base[0];  // slot 0 bucket head

#pragma unroll
    for (int r = 0; r < 9; ++r) {
        __syncthreads();  // all waves done reading Ms/Ws of slot r-1
        // ---- cooperative stage of full weight slice r ----
#pragma unroll
        for (int i = 0; i < NG; ++i) {
            int G = i * 512 + tid;
            int row = G >> 4, gg = G & 15;
            half8 v = *(const half8*)(Bt + (size_t)row * KDIM + r * 128 + gg * 8);
            *(half8*)&Ws[row][(gg ^ (row & 7)) * 8] = v;
        }
        half8 af_root[4];
        if (r < 8) {
            // ---- gather: this thread's (seg, 16 dims at p8*16) ----
            int truelen = cnts[r];
            int len = truelen < CAP ? truelen : CAP;
            float inv = truelen > 1 ? 1.f / (float)truelen : 1.f;
            const int4* bq = bq_base + r * CAPQ;
            int4 q0 = qpre;
            if (r < 7) qpre = bq_base[(r + 1) * CAPQ];  // prefetch next slot's head
            float c[16];
#pragma unroll
            for (int t = 0; t < 16; ++t) c[t] = 0.f;
            for (int j4 = 0; j4 < (len + 3) >> 2; ++j4) {
                int4 q = (j4 == 0) ? q0 : bq[j4];
                int ids[4] = {q.x, q.y, q.z, q.w};
                int base = j4 * 4;
#pragma unroll
                for (int t = 0; t < 4; ++t) {
                    if (base + t < len) {
                        const half8* rp = (const half8*)(act + (size_t)ids[t] * 128 + p8 * 16);
                        half8 v0 = rp[0], v1 = rp[1];   // 32B; 8 lanes cover the 256B row
#pragma unroll
                        for (int u = 0; u < 8; ++u) {
                            c[u] += (float)v0[u];
                            c[8 + u] += (float)v1[u];
                        }
                    }
                }
            }
            half8 o0, o1;
#pragma unroll
            for (int t = 0; t < 8; ++t) {
                o0[t] = (f16)(c[t] * inv);
                o1[t] = (f16)(c[8 + t] * inv);
            }
            int g0 = p8 * 2;
            *(half8*)&Ms[seg][(g0 ^ (seg & 7)) * 8] = o0;
            *(half8*)&Ms[seg][((g0 + 1) ^ (seg & 7)) * 8] = o1;
        } else {
            // root slot: A-frags direct from this wave's own node rows
            int arow = m0 + mt * 16 + l15;
            arow = arow < NNODES ? arow : NNODES - 1;
#pragma unroll
            for (int ks = 0; ks < 4; ++ks)
                af_root[ks] = *(const half8*)(act + (size_t)arow * 128 + ks * 32 + quad * 8);
        }
        __syncthreads();  // Ms + Ws visible
        // ---- MFMA ----
        const int arow = mt * 16 + l15;
#pragma unroll
        for (int ks = 0; ks < 4; ++ks) {
            int gi = ks * 4 + quad;
            half8 af = (r < 8) ? *(const half8*)&Ms[arow][(gi ^ (arow & 7)) * 8]
                               : af_root[ks];
#pragma unroll
            for (int nt = 0; nt < NT; ++nt) {
                int col = nh * (H / 2) + nt * 16 + l15;
                half8 bf = *(const half8*)&Ws[col][(gi ^ (col & 7)) * 8];
                acc[nt] = __builtin_amdgcn_mfma_f32_16x16x32_f16(af, bf, acc[nt], 0, 0, 0);
            }
        }
    }

    // ---- epilogue: D[m = quad*4+rg][n = l15] per n-tile ----
#pragma unroll
    for (int nt = 0; nt < NT; ++nt) {
        int col = nh * (H / 2) + nt * 16 + l15;
        float alpha, beta;
        if (MODE == 0) {
            float sc = g[col] * rsqrtf(rv[col] + 1e-5f);
            alpha = sc;
            beta = (bias[col] - rm[col]) * sc + be[col];
        } else {
            alpha = 1.f;
            beta = bias[col];
        }
#pragma unroll
        for (int rg = 0; rg < 4; ++rg) {
            int row = m0 + mt * 16 + quad * 4 + rg;
            if (row < NNODES) {
                float v = fmaf(acc[nt][rg], alpha, beta);
                if (MODE == 0) {
                    hout[(size_t)row * H + col] = (f16)fmaxf(v, 0.f);
                } else {
                    fout[(size_t)row * H + col] = 1.f / (1.f + __expf(-v));
                }
            }
        }
    }
}

extern "C" void kernel_launch(void* const* d_in, const int* in_sizes, int n_in,
                              void* d_out, int out_size, void* d_ws, size_t ws_size,
                              hipStream_t stream) {
    (void)in_sizes; (void)n_in; (void)out_size; (void)ws_size;
    const float* x   = (const float*)d_in[0];
    const int* ei    = (const int*)d_in[1];
    const int* et    = (const int*)d_in[2];
    const float* W1  = (const float*)d_in[3];
    const float* Wr1 = (const float*)d_in[4];
    const float* b1  = (const float*)d_in[5];
    const float* g1  = (const float*)d_in[6];
    const float* be1 = (const float*)d_in[7];
    const float* rm1 = (const float*)d_in[8];
    const float* rv1 = (const float*)d_in[9];
    const float* W2  = (const float*)d_in[10];
    const float* Wr2 = (const float*)d_in[11];
    const float* b2  = (const float*)d_in[12];
    const float* g2  = (const float*)d_in[13];
    const float* be2 = (const float*)d_in[14];
    const float* rm2 = (const float*)d_in[15];
    const float* rv2 = (const float*)d_in[16];
    const float* W3  = (const float*)d_in[17];
    const float* Wr3 = (const float*)d_in[18];
    const float* b3  = (const float*)d_in[19];
    const int* src = ei;
    const int* dst = ei + NEDGES;
    float* out = (float*)d_out;

    char* ws = (char*)d_ws;
    size_t off = 0;
    auto alloc = [&](size_t bytes) -> void* {
        off = (off + 255) & ~(size_t)255;
        void* p = ws + off;
        off += bytes;
        return p;
    };
    int* cnt  = (int*)alloc((size_t)NRSEG * 4);             // 1.6 MB
    int* esrc = (int*)alloc((size_t)NRSEG * CAP * 4);       // 25.6 MB
    f16* x16  = (f16*)alloc((size_t)NNODES * 128 * 2);      // 12.8 MB
    f16* ha   = (f16*)alloc((size_t)NNODES * 128 * 2);
    f16* hb   = (f16*)alloc((size_t)NNODES * 128 * 2);
    f16* Bt   = (f16*)alloc((size_t)320 * KDIM * 2);        // 0.74 MB (L1|L2|L3)

    hipMemsetAsync(cnt, 0, (size_t)NRSEG * 4, stream);
    bucket_fill<<<(NEDGES + 255) / 256, 256, 0, stream>>>(src, dst, et, cnt, esrc);
    setup_misc<<<(NNODES * 64 + 320 * KDIM + 255) / 256, 256, 0, stream>>>(
        x, x16, W1, Wr1, W2, Wr2, W3, Wr3, Bt);

    fused_layer<128, 0><<<NT64, 512, 0, stream>>>(x16, Bt, cnt, esrc,
                                                  b1, g1, be1, rm1, rv1, ha, nullptr);
    fused_layer<128, 0><<<NT64, 512, 0, stream>>>(ha, Bt + (size_t)128 * KDIM, cnt, esrc,
                                                  b2, g2, be2, rm2, rv2, hb, nullptr);
    fused_layer<64, 1><<<NT64, 512, 0, stream>>>(hb, Bt + (size_t)256 * KDIM, cnt, esrc,
                                                 b3, nullptr, nullptr, nullptr, nullptr,
                                                 nullptr, out);
}

// Round 13
// 434.628 us; speedup vs baseline: 1.4952x; 1.0969x over previous
//
#include <hip/hip_runtime.h>

typedef _Float16 f16;
typedef __attribute__((ext_vector_type(8))) _Float16 half8;
typedef __attribute__((ext_vector_type(2))) _Float16 half2v;
typedef __attribute__((ext_vector_type(4))) float float4v;

#define NNODES 50000
#define NEDGES 800000
#define NREL 8
#define NRSEG (NNODES * NREL)   // 400000 segments (dst, rel)
#define KDIM 1152               // (R+1)*128
#define CAP 16                  // bucket capacity: one 64B cacheline of indices
#define CAPQ (CAP / 4)
#define NT64 ((NNODES + 63) / 64)  // 782 tiles of 64 nodes

// one kernel builds the whole edge structure: count + bucket scatter
__global__ void bucket_fill(const int* __restrict__ src, const int* __restrict__ dst,
                            const int* __restrict__ et, int* __restrict__ cnt,
                            int* __restrict__ esrc) {
    int e = blockIdx.x * blockDim.x + threadIdx.x;
    if (e < NEDGES) {
        int s = dst[e] * NREL + et[e];
        int p = atomicAdd(&cnt[s], 1);
        if (p < CAP) esrc[s * CAP + p] = src[e];
    }
}

// merged setup: x->fp16, weights->fp16 Bt (rows 0..127 L1, 128..255 L2, 256..319 L3),
// and zero cnt (so no separate memset dispatch). Must run BEFORE bucket_fill.
__global__ void setup_misc(const float* __restrict__ x, f16* __restrict__ x16,
                           const float* __restrict__ W1, const float* __restrict__ Wr1,
                           const float* __restrict__ W2, const float* __restrict__ Wr2,
                           const float* __restrict__ W3, const float* __restrict__ Wr3,
                           f16* __restrict__ Bt, int* __restrict__ cnt) {
    int t = blockIdx.x * blockDim.x + threadIdx.x;
    if (t < NNODES * 64) {
        float2 v = ((const float2*)x)[t];
        half2v o = {(f16)v.x, (f16)v.y};
        ((half2v*)x16)[t] = o;
        return;
    }
    int idx = t - NNODES * 64;
    if (idx < 320 * KDIM) {
        int hg = idx / KDIM, k = idx - hg * KDIM;
        const float *W, *Wr;
        int h, H;
        if (hg < 128)      { W = W1; Wr = Wr1; h = hg;       H = 128; }
        else if (hg < 256) { W = W2; Wr = Wr2; h = hg - 128; H = 128; }
        else               { W = W3; Wr = Wr3; h = hg - 256; H = 64;  }
        float v = (k < 1024) ? W[(size_t)k * H + h] : Wr[(size_t)(k - 1024) * H + h];
        Bt[idx] = (f16)v;
        return;
    }
    int z = idx - 320 * KDIM;
    if (z < NRSEG / 4) ((int4*)cnt)[z] = (int4){0, 0, 0, 0};
}

// Fused RGCN layer (round-11 structure, COLS=64 per block).
// Block = (64-node tile, col-group of 64): 4 waves, wave w owns nodes
// [tile*64+16w, +16). Per slot r (8 rels + root): cooperative stage of the 16 KB
// weight slice into XOR-swizzled LDS (shared by 4 waves), gather into c[32] regs
// (lane (l15,quad) owns the 32 dims of its own MFMA A-frags), 2 barriers, MFMA from LDS.
// H=128: grid (NT64,2).  H=64: grid (NT64,1) — single gather, no duplication.
// MODE 0: bias+BN+ReLU -> fp16.  MODE 1: bias+sigmoid -> fp32.
template <int H, int MODE>
__global__ __launch_bounds__(256, 4) void fused_layer(
    const f16* __restrict__ act, const f16* __restrict__ Bt,
    const int* __restrict__ cnt, const int* __restrict__ esrc,
    const float* __restrict__ bias, const float* __restrict__ g,
    const float* __restrict__ be, const float* __restrict__ rm,
    const float* __restrict__ rv, f16* __restrict__ hout, float* __restrict__ fout) {
    constexpr int NT = 4;                // 4 n-tiles of 16 cols per wave
    __shared__ f16 Ws[64][128];          // 16 KB, XOR-swizzled granules
    const int tid = threadIdx.x;
    const int wave = tid >> 6, lane = tid & 63;
    const int l15 = lane & 15, quad = lane >> 4;
    const int m0 = blockIdx.x * 64 + wave * 16;  // this wave's 16 nodes
    const int nh = blockIdx.y;
    int node = m0 + l15;
    node = node < NNODES ? node : NNODES - 1;

    // per-relation counts for this node (two int4, broadcast across quads)
    int4 cq0 = ((const int4*)cnt)[node * 2];
    int4 cq1 = ((const int4*)cnt)[node * 2 + 1];
    int cnts[8] = {cq0.x, cq0.y, cq0.z, cq0.w, cq1.x, cq1.y, cq1.z, cq1.w};
    const int4* bq_base = (const int4*)esrc + (size_t)node * NREL * CAPQ;

    float4v acc[NT];
#pragma unroll
    for (int j = 0; j < NT; ++j) acc[j] = (float4v){0.f, 0.f, 0.f, 0.f};

    int4 qpre = bq_base[0];  // slot 0 bucket head
    half8 af_root[4];

#pragma unroll
    for (int r = 0; r < 9; ++r) {
        __syncthreads();  // all waves done reading Ws of slot r-1
        // ---- cooperative stage of weight slice r into swizzled LDS ----
#pragma unroll
        for (int i = 0; i < 4; ++i) {
            int G = i * 256 + tid;       // granule id: row = G>>4, g = G&15
            int row = G >> 4, gg = G & 15;
            half8 v = *(const half8*)(Bt + (size_t)(nh * 64 + row) * KDIM +
                                      r * 128 + gg * 8);
            *(half8*)&Ws[row][((gg ^ (row & 7))) * 8] = v;
        }
        // ---- gather phase (overlaps staging latency) ----
        float c[32];
        if (r < 8) {
            int truelen = cnts[r];
            int len = truelen < CAP ? truelen : CAP;
            float inv = truelen > 1 ? 1.f / (float)truelen : 1.f;
            const int4* bq = bq_base + r * CAPQ;
            int4 q0 = qpre;
            if (r < 7) qpre = bq_base[(r + 1) * CAPQ];  // prefetch next slot's head
#pragma unroll
            for (int t = 0; t < 32; ++t) c[t] = 0.f;
            for (int j4 = 0; j4 < (len + 3) >> 2; ++j4) {
                int4 q = (j4 == 0) ? q0 : bq[j4];
                int ids[4] = {q.x, q.y, q.z, q.w};
                int base = j4 * 4;
#pragma unroll
                for (int t = 0; t < 4; ++t) {
                    if (base + t < len) {
                        // 4 half8 loads at 64B stride; quads 0..3 tile each 64B chunk
                        const half8* rp = (const half8*)(act + (size_t)ids[t] * 128 + quad * 8);
                        half8 v0 = rp[0], v1 = rp[4], v2 = rp[8], v3 = rp[12];
#pragma unroll
                        for (int u = 0; u < 8; ++u) {
                            c[u] += (float)v0[u];
                            c[8 + u] += (float)v1[u];
                            c[16 + u] += (float)v2[u];
                            c[24 + u] += (float)v3[u];
                        }
                    }
                }
            }
#pragma unroll
            for (int t = 0; t < 32; ++t) c[t] *= inv;
        } else {
            // root slot: prefetch own act row (A-frag layout matches directly)
#pragma unroll
            for (int ks = 0; ks < 4; ++ks)
                af_root[ks] = *(const half8*)(act + (size_t)node * 128 + ks * 32 + quad * 8);
        }
        __syncthreads();  // Ws visible
        // ---- MFMA from LDS ----
#pragma unroll
        for (int ks = 0; ks < 4; ++ks) {
            half8 af;
            if (r < 8) {
#pragma unroll
                for (int u = 0; u < 8; ++u) af[u] = (f16)c[ks * 8 + u];
            } else {
                af = af_root[ks];
            }
#pragma unroll
            for (int nt = 0; nt < NT; ++nt) {
                int row = nt * 16 + l15;
                half8 bf = *(const half8*)&Ws[row][(((ks * 4 + quad) ^ (row & 7))) * 8];
                acc[nt] = __builtin_amdgcn_mfma_f32_16x16x32_f16(af, bf, acc[nt], 0, 0, 0);
            }
        }
    }

    // ---- epilogue: D[m = quad*4+rg][n = l15] per n-tile ----
#pragma unroll
    for (int nt = 0; nt < NT; ++nt) {
        int col = nh * 64 + nt * 16 + l15;
        float alpha, beta;
        if (MODE == 0) {
            float sc = g[col] * rsqrtf(rv[col] + 1e-5f);
            alpha = sc;
            beta = (bias[col] - rm[col]) * sc + be[col];
        } else {
            alpha = 1.f;
            beta = bias[col];
        }
#pragma unroll
        for (int rg = 0; rg < 4; ++rg) {
            int row = m0 + quad * 4 + rg;
            if (row < NNODES) {
                float v = fmaf(acc[nt][rg], alpha, beta);
                if (MODE == 0) {
                    hout[(size_t)row * H + col] = (f16)fmaxf(v, 0.f);
                } else {
                    fout[(size_t)row * H + col] = 1.f / (1.f + __expf(-v));
                }
            }
        }
    }
}

extern "C" void kernel_launch(void* const* d_in, const int* in_sizes, int n_in,
                              void* d_out, int out_size, void* d_ws, size_t ws_size,
                              hipStream_t stream) {
    (void)in_sizes; (void)n_in; (void)out_size; (void)ws_size;
    const float* x   = (const float*)d_in[0];
    const int* ei    = (const int*)d_in[1];
    const int* et    = (const int*)d_in[2];
    const float* W1  = (const float*)d_in[3];
    const float* Wr1 = (const float*)d_in[4];
    const float* b1  = (const float*)d_in[5];
    const float* g1  = (const float*)d_in[6];
    const float* be1 = (const float*)d_in[7];
    const float* rm1 = (const float*)d_in[8];
    const float* rv1 = (const float*)d_in[9];
    const float* W2  = (const float*)d_in[10];
    const float* Wr2 = (const float*)d_in[11];
    const float* b2  = (const float*)d_in[12];
    const float* g2  = (const float*)d_in[13];
    const float* be2 = (const float*)d_in[14];
    const float* rm2 = (const float*)d_in[15];
    const float* rv2 = (const float*)d_in[16];
    const float* W3  = (const float*)d_in[17];
    const float* Wr3 = (const float*)d_in[18];
    const float* b3  = (const float*)d_in[19];
    const int* src = ei;
    const int* dst = ei + NEDGES;
    float* out = (float*)d_out;

    char* ws = (char*)d_ws;
    size_t off = 0;
    auto alloc = [&](size_t bytes) -> void* {
        off = (off + 255) & ~(size_t)255;
        void* p = ws + off;
        off += bytes;
        return p;
    };
    int* cnt  = (int*)alloc((size_t)NRSEG * 4);             // 1.6 MB
    int* esrc = (int*)alloc((size_t)NRSEG * CAP * 4);       // 25.6 MB
    f16* x16  = (f16*)alloc((size_t)NNODES * 128 * 2);      // 12.8 MB
    f16* ha   = (f16*)alloc((size_t)NNODES * 128 * 2);
    f16* hb   = (f16*)alloc((size_t)NNODES * 128 * 2);
    f16* Bt   = (f16*)alloc((size_t)320 * KDIM * 2);        // 0.74 MB (L1|L2|L3)

    // setup (also zeroes cnt) must precede bucket_fill
    const int SETUP_T = NNODES * 64 + 320 * KDIM + NRSEG / 4;
    setup_misc<<<(SETUP_T + 255) / 256, 256, 0, stream>>>(
        x, x16, W1, Wr1, W2, Wr2, W3, Wr3, Bt, cnt);
    bucket_fill<<<(NEDGES + 255) / 256, 256, 0, stream>>>(src, dst, et, cnt, esrc);

    fused_layer<128, 0><<<dim3(NT64, 2), 256, 0, stream>>>(x16, Bt, cnt, esrc,
                                                           b1, g1, be1, rm1, rv1, ha, nullptr);
    fused_layer<128, 0><<<dim3(NT64, 2), 256, 0, stream>>>(ha, Bt + (size_t)128 * KDIM, cnt, esrc,
                                                           b2, g2, be2, rm2, rv2, hb, nullptr);
    fused_layer<64, 1><<<dim3(NT64, 1), 256, 0, stream>>>(hb, Bt + (size_t)256 * KDIM, cnt, esrc,
                                                          b3, nullptr, nullptr, nullptr, nullptr,
                                                          nullptr, out);
}